// Round 9
// baseline (370.364 us; speedup 1.0000x reference)
//
#include <hip/hip_runtime.h>
#include <hip/hip_fp16.h>

// ---------------------------------------------------------------------------
// GCN 4-layer forward on MI355X (gfx950).
//   Preprocess (ZERO global atomics): LDS range histograms (8 ranges x 64
//     chunks) + per-edge bucket rank -> reduce+norms -> scan -> cursor bases
//     -> single-pass CSR scatter -> per-node src-range counting sort
//     (makes the per-layer gathers sweep h in address order => L2-resident).
//   Per layer : bf16-split MFMA GEMM (3-term, ~fp32 precision), B staged in
//     LDS (XOR-swizzled); L0 reads x fp32 directly (split fused into A-load).
//     h in fp16 -> CSR gather with 16-lane/16B row segments (4 nodes/wave),
//     fused epilogue + bf16 hi/lo split.
// ---------------------------------------------------------------------------

typedef __attribute__((ext_vector_type(8))) short short8;
typedef __attribute__((ext_vector_type(4))) float f32x4;

#define NRANGE 8
#define NCHUNK 64
#define RMAX   6272   // 8*6272 = 50176 >= 50000 nodes

__device__ inline unsigned short bf16_rne(float v) {
    union { float f; unsigned u; } c; c.f = v;
    unsigned u = c.u;
    unsigned lsb = (u >> 16) & 1u;
    u += 0x7fffu + lsb;
    return (unsigned short)(u >> 16);
}
__device__ inline float bf16_to_f(unsigned short h) {
    union { unsigned u; float f; } c; c.u = ((unsigned)h) << 16;
    return c.f;
}
__device__ inline void split_bf16(float v, unsigned short& hi, unsigned short& lo) {
    hi = bf16_rne(v);
    lo = bf16_rne(v - bf16_to_f(hi));
}

// ---------------------------------------------------------------------------
// Preprocessing — LDS-privatized histograms + per-edge bucket rank.
// ---------------------------------------------------------------------------

__global__ __launch_bounds__(256) void k_hist(const int* __restrict__ src,
                                              const int* __restrict__ dst,
                                              int ne, int R, int E,
                                              int* __restrict__ cnt_s,
                                              int* __restrict__ cnt_d,
                                              int* __restrict__ pos) {
    __shared__ int hs[RMAX];
    __shared__ int hd[RMAX];
    int r = blockIdx.x & (NRANGE - 1);
    int c = blockIdx.x >> 3;
    int tid = threadIdx.x;
    for (int i = tid; i < R; i += 256) { hs[i] = 0; hd[i] = 0; }
    __syncthreads();
    int lo = r * R, hi = lo + R;
    int e0 = c * E, e1 = min(e0 + E, ne);
    for (int i = e0 + tid; i < e1; i += 256) {
        int s = src[i], d = dst[i];
        if (s >= lo && s < hi) atomicAdd(&hs[s - lo], 1);
        if (d >= lo && d < hi) {
            int p = atomicAdd(&hd[d - lo], 1);
            pos[i] = p;                     // rank within (r,c,node) bucket
        }
    }
    __syncthreads();
    int base = (r * NCHUNK + c) * R;
    for (int i = tid; i < R; i += 256) {
        cnt_s[base + i] = hs[i];
        cnt_d[base + i] = hd[i];
    }
}

__global__ void k_reduce_norms(const int* __restrict__ cnt_s,
                               const int* __restrict__ cnt_d, int R, int n,
                               float* __restrict__ onrm, float* __restrict__ inrm,
                               int* __restrict__ degd_sum) {
    int i = blockIdx.x * blockDim.x + threadIdx.x;
    if (i >= NRANGE * R) return;
    int r = i / R, ip = i - r * R;
    int ds = 0, dd = 0;
    for (int c = 0; c < NCHUNK; ++c) {
        ds += cnt_s[(r * NCHUNK + c) * R + ip];
        dd += cnt_d[(r * NCHUNK + c) * R + ip];
    }
    degd_sum[i] = dd;
    if (i < n) {
        onrm[i] = rsqrtf((float)max(ds, 1));
        inrm[i] = rsqrtf((float)max(dd, 1));
    }
}

// Single-block exclusive scan, int4 per thread.
__global__ __launch_bounds__(1024) void k_scan(const int* __restrict__ deg, int n,
                                               int* __restrict__ row_ptr) {
    __shared__ int wsum[16];
    __shared__ int carry;
    int tid = threadIdx.x;
    int lane = tid & 63;
    int wid = tid >> 6;
    if (tid == 0) carry = 0;
    __syncthreads();
    int n4 = (n + 3) >> 2;
    for (int base = 0; base < n4; base += 1024) {
        int i4 = base + tid;
        int4 v = make_int4(0, 0, 0, 0);
        if (i4 < n4) v = ((const int4*)deg)[i4];
        int s = v.x + v.y + v.z + v.w;
        int x = s;
#pragma unroll
        for (int off = 1; off < 64; off <<= 1) {
            int y = __shfl_up(x, off, 64);
            if (lane >= off) x += y;
        }
        if (lane == 63) wsum[wid] = x;
        __syncthreads();
        if (wid == 0 && lane < 16) {
            int w = wsum[lane];
#pragma unroll
            for (int off = 1; off < 16; off <<= 1) {
                int y = __shfl_up(w, off, 16);
                if (lane >= off) w += y;
            }
            wsum[lane] = w;
        }
        __syncthreads();
        int excl = x - s + carry + (wid > 0 ? wsum[wid - 1] : 0);
        if (i4 < n4) {
            int e0 = excl, e1 = e0 + v.x, e2 = e1 + v.y, e3 = e2 + v.z;
            ((int4*)row_ptr)[i4] = make_int4(e0, e1, e2, e3);
        }
        __syncthreads();
        if (tid == 0) carry += wsum[15];
        __syncthreads();
    }
    if (tid == 0) row_ptr[n] = carry;
}

__global__ void k_cursors(const int* __restrict__ row_ptr,
                          const int* __restrict__ cnt_d, int R, int n,
                          int* __restrict__ cbase) {
    int i = blockIdx.x * blockDim.x + threadIdx.x;
    if (i >= NRANGE * R) return;
    int r = i / R, ip = i - r * R;
    int run = (i < n) ? row_ptr[i] : 0;
    for (int c = 0; c < NCHUNK; ++c) {
        int idx = (r * NCHUNK + c) * R + ip;
        cbase[idx] = run;
        run += cnt_d[idx];
    }
}

__global__ void k_csr_scatter(const int* __restrict__ src,
                              const int* __restrict__ dst,
                              const int* __restrict__ pos,
                              const int* __restrict__ cbase,
                              int ne, int R, int E,
                              int* __restrict__ eidx) {
    int i = blockIdx.x * blockDim.x + threadIdx.x;
    if (i >= ne) return;
    int d = dst[i];
    int r = d / R, ip = d - r * R;
    int c = i / E;
    eidx[cbase[(r * NCHUNK + c) * R + ip] + pos[i]] = src[i];
}

// Per-node counting sort by src-range (8 buckets). Makes every node's edge
// list sweep h in address order -> the hot gather working set at any instant
// is ~2 ranges (~3 MB) which fits a 4 MiB XCD L2.
__global__ void k_sortnode(const int* __restrict__ row_ptr,
                           const int* __restrict__ eidx,
                           int* __restrict__ eidx2, int n, int Rs) {
    int v = blockIdx.x * blockDim.x + threadIdx.x;
    if (v >= n) return;
    int beg = row_ptr[v], end = row_ptr[v + 1];
    int c[8] = {0, 0, 0, 0, 0, 0, 0, 0};
    for (int j = beg; j < end; ++j) c[eidx[j] / Rs]++;
    int p[8]; int run = 0;
#pragma unroll
    for (int r = 0; r < 8; ++r) { p[r] = run; run += c[r]; }
    for (int j = beg; j < end; ++j) {
        int s = eidx[j];
        int r = s / Rs;
        eidx2[beg + p[r]++] = s;
    }
}

// ---------------------------------------------------------------------------
// Weight split (transposed, bf16 hi/lo)
// ---------------------------------------------------------------------------

__global__ void k_split_w_all(const float* __restrict__ W0, const float* __restrict__ W1,
                              const float* __restrict__ W2, const float* __restrict__ W3,
                              unsigned short* __restrict__ Wh0, unsigned short* __restrict__ Wl0,
                              unsigned short* __restrict__ Wh1, unsigned short* __restrict__ Wl1,
                              unsigned short* __restrict__ Wh2, unsigned short* __restrict__ Wl2,
                              unsigned short* __restrict__ Wh3, unsigned short* __restrict__ Wl3) {
    int i = blockIdx.x * blockDim.x + threadIdx.x;
    const float* W; unsigned short *Wh, *Wl; int K, F, off;
    if (i < 32768)                    { W = W0; Wh = Wh0; Wl = Wl0; K = 256; F = 128; off = i; }
    else if (i < 32768 + 16384)       { W = W1; Wh = Wh1; Wl = Wl1; K = 128; F = 128; off = i - 32768; }
    else if (i < 32768 + 32768)       { W = W2; Wh = Wh2; Wl = Wl2; K = 128; F = 128; off = i - 49152; }
    else if (i < 32768 + 32768 + 8192){ W = W3; Wh = Wh3; Wl = Wl3; K = 128; F = 64;  off = i - 65536; }
    else return;
    int k = off / F, c = off % F;
    unsigned short h, l;
    split_bf16(W[k * F + c], h, l);
    Wh[c * K + k] = h;
    Wl[c * K + k] = l;
}

// ---------------------------------------------------------------------------
// MFMA GEMM: H[m][c] = sum_k A[m][k]*W[k][c]; H stored fp16.
// FA=true: A read from fp32 X, *onrm + bf16 split fused into fragment load.
// ---------------------------------------------------------------------------
template <int K, int N, bool FA>
__global__ __launch_bounds__(256) void k_mm(const unsigned short* __restrict__ Ah,
                                            const unsigned short* __restrict__ Al,
                                            const float* __restrict__ Xf,
                                            const float* __restrict__ onrm,
                                            const unsigned short* __restrict__ Bh,
                                            const unsigned short* __restrict__ Bl,
                                            __half* __restrict__ H, int n) {
    constexpr int KT = 128;
    constexpr int NT = N / 16;
    constexpr int NKT = K / KT;
    __shared__ unsigned short sBh[N * KT];
    __shared__ unsigned short sBl[N * KT];

    int tid = threadIdx.x;
    int w = tid >> 6, lane = tid & 63;
    int quad = lane >> 4, l16 = lane & 15;
    int row_base = blockIdx.x * 128 + w * 32;

    int ar0 = row_base + l16;
    int ar1 = row_base + 16 + l16;
    if (ar0 >= n) ar0 = n - 1;
    if (ar1 >= n) ar1 = n - 1;

    float on0 = 0.f, on1 = 0.f;
    if (FA) { on0 = onrm[ar0]; on1 = onrm[ar1]; }

    f32x4 acc[2][NT];
#pragma unroll
    for (int m = 0; m < 2; ++m)
#pragma unroll
        for (int t = 0; t < NT; ++t) acc[m][t] = (f32x4){0.f, 0.f, 0.f, 0.f};

    for (int kt = 0; kt < NKT; ++kt) {
        if (kt) __syncthreads();
        for (int idx = tid; idx < N * 16; idx += 256) {
            int c = idx >> 4;
            int g = idx & 15;
            short8 vh = *(const short8*)(Bh + (size_t)c * K + kt * KT + g * 8);
            short8 vl = *(const short8*)(Bl + (size_t)c * K + kt * KT + g * 8);
            int sg = g ^ (c & 15);
            *(short8*)(&sBh[c * KT + sg * 8]) = vh;
            *(short8*)(&sBl[c * KT + sg * 8]) = vl;
        }
        __syncthreads();

#pragma unroll
        for (int k0 = 0; k0 < KT; k0 += 32) {
            int eoff = k0 + quad * 8;
            short8 a0hv, a0lv, a1hv, a1lv;
            if (FA) {
                const float* x0 = Xf + (size_t)ar0 * K + kt * KT + eoff;
                const float* x1 = Xf + (size_t)ar1 * K + kt * KT + eoff;
                float4 p00 = *(const float4*)x0;
                float4 p01 = *(const float4*)(x0 + 4);
                float4 p10 = *(const float4*)x1;
                float4 p11 = *(const float4*)(x1 + 4);
                float e0[8] = {p00.x, p00.y, p00.z, p00.w, p01.x, p01.y, p01.z, p01.w};
                float e1[8] = {p10.x, p10.y, p10.z, p10.w, p11.x, p11.y, p11.z, p11.w};
#pragma unroll
                for (int q = 0; q < 8; ++q) {
                    unsigned short hh, ll;
                    split_bf16(e0[q] * on0, hh, ll);
                    a0hv[q] = (short)hh; a0lv[q] = (short)ll;
                    split_bf16(e1[q] * on1, hh, ll);
                    a1hv[q] = (short)hh; a1lv[q] = (short)ll;
                }
            } else {
                a0hv = *(const short8*)(Ah + (size_t)ar0 * K + kt * KT + eoff);
                a0lv = *(const short8*)(Al + (size_t)ar0 * K + kt * KT + eoff);
                a1hv = *(const short8*)(Ah + (size_t)ar1 * K + kt * KT + eoff);
                a1lv = *(const short8*)(Al + (size_t)ar1 * K + kt * KT + eoff);
            }
            int g = (k0 >> 3) + quad;
            int sg8 = (g ^ l16) * 8;
#pragma unroll
            for (int t = 0; t < NT; ++t) {
                int cb = (t * 16 + l16) * KT;
                short8 bh = *(const short8*)(&sBh[cb + sg8]);
                short8 bl = *(const short8*)(&sBl[cb + sg8]);
                acc[0][t] = __builtin_amdgcn_mfma_f32_16x16x32_bf16(a0hv, bh, acc[0][t], 0, 0, 0);
                acc[0][t] = __builtin_amdgcn_mfma_f32_16x16x32_bf16(a0lv, bh, acc[0][t], 0, 0, 0);
                acc[0][t] = __builtin_amdgcn_mfma_f32_16x16x32_bf16(a0hv, bl, acc[0][t], 0, 0, 0);
                acc[1][t] = __builtin_amdgcn_mfma_f32_16x16x32_bf16(a1hv, bh, acc[1][t], 0, 0, 0);
                acc[1][t] = __builtin_amdgcn_mfma_f32_16x16x32_bf16(a1lv, bh, acc[1][t], 0, 0, 0);
                acc[1][t] = __builtin_amdgcn_mfma_f32_16x16x32_bf16(a1hv, bl, acc[1][t], 0, 0, 0);
            }
        }
    }

#pragma unroll
    for (int m = 0; m < 2; ++m) {
#pragma unroll
        for (int t = 0; t < NT; ++t) {
#pragma unroll
            for (int r = 0; r < 4; ++r) {
                int grow = row_base + m * 16 + quad * 4 + r;
                if (grow < n) H[(size_t)grow * N + t * 16 + l16] = __float2half(acc[m][t][r]);
            }
        }
    }
}

// ---------------------------------------------------------------------------
// Aggregation: 16-lane row segments, 4 nodes/wave. FO=128: 16B/lane (one
// dwordx4 = 4 rows/wave-instr), unroll 4.
// ---------------------------------------------------------------------------

__global__ __launch_bounds__(256) void k_agg128_split(const __half* __restrict__ h,
                                                      const int* __restrict__ row_ptr,
                                                      const int* __restrict__ eidx,
                                                      const float* __restrict__ inrm,
                                                      const float* __restrict__ onrm,
                                                      const float* __restrict__ bias,
                                                      unsigned short* __restrict__ Ah,
                                                      unsigned short* __restrict__ Al, int n) {
    int wave = threadIdx.x >> 6;
    int lane = threadIdx.x & 63;
    int g = lane >> 4;
    int l = lane & 15;
    int node = blockIdx.x * 16 + wave * 4 + g;
    bool valid = node < n;
    int nd = valid ? node : n - 1;
    int beg = row_ptr[nd], end = row_ptr[nd + 1];
    const short8* h8 = (const short8*)h;   // row = 16 granules of 16B

    float a[4][8];
#pragma unroll
    for (int u = 0; u < 4; ++u)
#pragma unroll
        for (int c = 0; c < 8; ++c) a[u][c] = 0.f;

    int j = beg;
    for (; j + 4 <= end; j += 4) {
        int s[4];
#pragma unroll
        for (int u = 0; u < 4; ++u) s[u] = eidx[j + u];
        short8 v[4];
#pragma unroll
        for (int u = 0; u < 4; ++u) v[u] = h8[(size_t)s[u] * 16 + l];
#pragma unroll
        for (int u = 0; u < 4; ++u) {
            const __half2* ph = reinterpret_cast<const __half2*>(&v[u]);
#pragma unroll
            for (int p = 0; p < 4; ++p) {
                float2 f = __half22float2(ph[p]);
                a[u][2 * p] += f.x;
                a[u][2 * p + 1] += f.y;
            }
        }
    }
    for (; j < end; ++j) {
        short8 v = h8[(size_t)eidx[j] * 16 + l];
        const __half2* ph = reinterpret_cast<const __half2*>(&v);
#pragma unroll
        for (int p = 0; p < 4; ++p) {
            float2 f = __half22float2(ph[p]);
            a[0][2 * p] += f.x;
            a[0][2 * p + 1] += f.y;
        }
    }

    float nrm = inrm[nd];
    float on = onrm[nd];
    float4 b0 = ((const float4*)bias)[l * 2];
    float4 b1 = ((const float4*)bias)[l * 2 + 1];
    float bb[8] = {b0.x, b0.y, b0.z, b0.w, b1.x, b1.y, b1.z, b1.w};
    short8 hv, lv;
#pragma unroll
    for (int c = 0; c < 8; ++c) {
        float s = (a[0][c] + a[1][c]) + (a[2][c] + a[3][c]);
        float o = fmaxf(s * nrm + bb[c], 0.f) * on;
        unsigned short hh, ll;
        split_bf16(o, hh, ll);
        hv[c] = (short)hh;
        lv[c] = (short)ll;
    }
    if (valid) {
        ((short8*)Ah)[(size_t)node * 16 + l] = hv;
        ((short8*)Al)[(size_t)node * 16 + l] = lv;
    }
}

// FO=64 final layer: 16-lane x 8B segments (4 nodes/wave), unroll 8, fp32 out.
__global__ __launch_bounds__(256) void k_agg64(const __half* __restrict__ h,
                                               const int* __restrict__ row_ptr,
                                               const int* __restrict__ eidx,
                                               const float* __restrict__ inrm,
                                               const float* __restrict__ bias,
                                               float* __restrict__ out, int n) {
    int wave = threadIdx.x >> 6;
    int lane = threadIdx.x & 63;
    int g = lane >> 4;
    int l = lane & 15;
    int node = blockIdx.x * 16 + wave * 4 + g;
    bool valid = node < n;
    int nd = valid ? node : n - 1;
    int beg = row_ptr[nd], end = row_ptr[nd + 1];
    const ushort4* h4 = (const ushort4*)h;  // row = 16 granules of 8B

    float a[8][4];
#pragma unroll
    for (int u = 0; u < 8; ++u)
#pragma unroll
        for (int c = 0; c < 4; ++c) a[u][c] = 0.f;

    int j = beg;
    for (; j + 8 <= end; j += 8) {
        int s[8];
#pragma unroll
        for (int u = 0; u < 8; ++u) s[u] = eidx[j + u];
        ushort4 v[8];
#pragma unroll
        for (int u = 0; u < 8; ++u) v[u] = h4[(size_t)s[u] * 16 + l];
#pragma unroll
        for (int u = 0; u < 8; ++u) {
            const __half2* ph = reinterpret_cast<const __half2*>(&v[u]);
            float2 f0 = __half22float2(ph[0]);
            float2 f1 = __half22float2(ph[1]);
            a[u][0] += f0.x; a[u][1] += f0.y; a[u][2] += f1.x; a[u][3] += f1.y;
        }
    }
    for (; j < end; ++j) {
        ushort4 v = h4[(size_t)eidx[j] * 16 + l];
        const __half2* ph = reinterpret_cast<const __half2*>(&v);
        float2 f0 = __half22float2(ph[0]);
        float2 f1 = __half22float2(ph[1]);
        a[0][0] += f0.x; a[0][1] += f0.y; a[0][2] += f1.x; a[0][3] += f1.y;
    }

    float nrm = inrm[nd];
    float4 b4 = ((const float4*)bias)[l];
    float4 o;
    float s0 = ((a[0][0] + a[1][0]) + (a[2][0] + a[3][0])) + ((a[4][0] + a[5][0]) + (a[6][0] + a[7][0]));
    float s1 = ((a[0][1] + a[1][1]) + (a[2][1] + a[3][1])) + ((a[4][1] + a[5][1]) + (a[6][1] + a[7][1]));
    float s2 = ((a[0][2] + a[1][2]) + (a[2][2] + a[3][2])) + ((a[4][2] + a[5][2]) + (a[6][2] + a[7][2]));
    float s3 = ((a[0][3] + a[1][3]) + (a[2][3] + a[3][3])) + ((a[4][3] + a[5][3]) + (a[6][3] + a[7][3]));
    o.x = s0 * nrm + b4.x;
    o.y = s1 * nrm + b4.y;
    o.z = s2 * nrm + b4.z;
    o.w = s3 * nrm + b4.w;
    if (valid) ((float4*)out)[(size_t)node * 16 + l] = o;
}

// ---------------------------------------------------------------------------
// Fallback fp32 path (known-good) — used if workspace too small for MFMA path.
// ---------------------------------------------------------------------------
template <int K, int FO, int TX, int TY, int RPT>
__global__ __launch_bounds__(256) void k_matmul(const float* __restrict__ X,
                                                const float* __restrict__ W,
                                                const float* __restrict__ onrm,
                                                float* __restrict__ H, int n) {
    constexpr int BROWS = TY * RPT;
    constexpr int LDK = K + 1;
    __shared__ float xs[BROWS * LDK];
    int tx = threadIdx.x, ty = threadIdx.y;
    int tid = ty * TX + tx;
    int row0 = blockIdx.x * BROWS;

    for (int idx = tid; idx < BROWS * K; idx += 256) {
        int r = idx / K;
        int k = idx - r * K;
        int row = row0 + r;
        xs[r * LDK + k] = (row < n) ? X[(size_t)row * K + k] : 0.f;
    }
    __syncthreads();

    float4 acc[RPT];
#pragma unroll
    for (int r = 0; r < RPT; ++r) acc[r] = make_float4(0.f, 0.f, 0.f, 0.f);

    const float4* W4 = (const float4*)W;
#pragma unroll 4
    for (int k = 0; k < K; ++k) {
        float4 w = W4[k * (FO / 4) + tx];
#pragma unroll
        for (int r = 0; r < RPT; ++r) {
            float xv = xs[(ty * RPT + r) * LDK + k];
            acc[r].x += xv * w.x;
            acc[r].y += xv * w.y;
            acc[r].z += xv * w.z;
            acc[r].w += xv * w.w;
        }
    }

#pragma unroll
    for (int r = 0; r < RPT; ++r) {
        int row = row0 + ty * RPT + r;
        if (row < n) {
            float s = onrm[row];
            float4 o = make_float4(acc[r].x * s, acc[r].y * s, acc[r].z * s, acc[r].w * s);
            ((float4*)H)[(size_t)row * (FO / 4) + tx] = o;
        }
    }
}

__global__ __launch_bounds__(256) void k_agg128f(const float* __restrict__ h,
                                                 const int* __restrict__ row_ptr,
                                                 const int* __restrict__ eidx,
                                                 const float* __restrict__ inrm,
                                                 const float* __restrict__ bias,
                                                 float* __restrict__ out, int n, int relu) {
    int node = blockIdx.x * 4 + (threadIdx.x >> 6);
    int lane = threadIdx.x & 63;
    if (node >= n) return;
    int beg = row_ptr[node], end = row_ptr[node + 1];
    const float2* h2 = (const float2*)h;
    float ax = 0.f, ay = 0.f;
    for (int j = beg; j < end; ++j) {
        int s = eidx[j];
        float2 v = h2[(size_t)s * 64 + lane];
        ax += v.x;
        ay += v.y;
    }
    float nrm = inrm[node];
    float2 b2 = ((const float2*)bias)[lane];
    float ox = ax * nrm + b2.x;
    float oy = ay * nrm + b2.y;
    if (relu) { ox = fmaxf(ox, 0.f); oy = fmaxf(oy, 0.f); }
    float2 o; o.x = ox; o.y = oy;
    ((float2*)out)[(size_t)node * 64 + lane] = o;
}

__global__ __launch_bounds__(256) void k_agg64f(const float* __restrict__ h,
                                                const int* __restrict__ row_ptr,
                                                const int* __restrict__ eidx,
                                                const float* __restrict__ inrm,
                                                const float* __restrict__ bias,
                                                float* __restrict__ out, int n) {
    int node = blockIdx.x * 4 + (threadIdx.x >> 6);
    int lane = threadIdx.x & 63;
    if (node >= n) return;
    int beg = row_ptr[node], end = row_ptr[node + 1];
    float acc = 0.f;
    for (int j = beg; j < end; ++j) {
        int s = eidx[j];
        acc += h[(size_t)s * 64 + lane];
    }
    out[(size_t)node * 64 + lane] = acc * inrm[node] + bias[lane];
}

// Legacy atomic preprocessing (only if n > NRANGE*RMAX; never for this problem)
__global__ void k_degrees_leg(const int* __restrict__ src, const int* __restrict__ dst,
                              int ne, int* __restrict__ degs, int* __restrict__ degd) {
    int i = blockIdx.x * blockDim.x + threadIdx.x;
    if (i < ne) {
        atomicAdd(&degs[src[i]], 1);
        atomicAdd(&degd[dst[i]], 1);
    }
}
__global__ void k_norms_leg(const int* __restrict__ degs, const int* __restrict__ degd,
                            float* __restrict__ onrm, float* __restrict__ inrm,
                            int* __restrict__ degd_sum, int n) {
    int i = blockIdx.x * blockDim.x + threadIdx.x;
    if (i < n) {
        degd_sum[i] = degd[i];
        onrm[i] = rsqrtf((float)max(degs[i], 1));
        inrm[i] = rsqrtf((float)max(degd[i], 1));
    }
}
__global__ void k_copy_int(const int* __restrict__ a, int* __restrict__ b, int n) {
    int i = blockIdx.x * blockDim.x + threadIdx.x;
    if (i < n) b[i] = a[i];
}
__global__ void k_build_csr_leg(const int* __restrict__ src, const int* __restrict__ dst,
                                int ne, int* __restrict__ cursor, int* __restrict__ eidx) {
    int i = blockIdx.x * blockDim.x + threadIdx.x;
    if (i < ne) {
        int p = atomicAdd(&cursor[dst[i]], 1);
        eidx[p] = src[i];
    }
}

static inline size_t align_up(size_t v, size_t a) { return (v + a - 1) & ~(a - 1); }

extern "C" void kernel_launch(void* const* d_in, const int* in_sizes, int n_in,
                              void* d_out, int out_size, void* d_ws, size_t ws_size,
                              hipStream_t stream) {
    const float* x  = (const float*)d_in[0];
    const int* ei   = (const int*)d_in[1];
    const float* W0 = (const float*)d_in[2];
    const float* b0 = (const float*)d_in[3];
    const float* W1 = (const float*)d_in[4];
    const float* b1 = (const float*)d_in[5];
    const float* W2 = (const float*)d_in[6];
    const float* b2 = (const float*)d_in[7];
    const float* W3 = (const float*)d_in[8];
    const float* b3 = (const float*)d_in[9];

    const int n  = in_sizes[0] / 256;   // 50000
    const int ne = in_sizes[1] / 2;     // 800000
    const int n_pad = (n + 127) & ~127;
    const int* src = ei;
    const int* dst = ei + ne;

    // ---- shared layout ----
    char* ws = (char*)d_ws;
    size_t off = 0;
    auto take = [&](size_t bytes) { void* p = ws + off; off = align_up(off + bytes, 256); return p; };
    int* row_ptr  = (int*)take((size_t)(n_pad + 4) * 4);
    int* degd_sum = (int*)take((size_t)n_pad * 4);
    int* eidx     = (int*)take((size_t)ne * 4);
    int* eidx2    = (int*)take((size_t)ne * 4);   // src-range-sorted edge lists
    float* onrm   = (float*)take((size_t)n * 4);
    float* inrm   = (float*)take((size_t)n * 4);

    // ---- MFMA-path layout ----
    size_t off_save = off;
    unsigned short* Ah  = (unsigned short*)take((size_t)n_pad * 256 * 2);
    unsigned short* Al  = (unsigned short*)take((size_t)n_pad * 256 * 2);
    __half* hbuf        = (__half*)take((size_t)n * 128 * 2);
    unsigned short* Wh0 = (unsigned short*)take(256 * 128 * 2);
    unsigned short* Wl0 = (unsigned short*)take(256 * 128 * 2);
    unsigned short* Wh1 = (unsigned short*)take(128 * 128 * 2);
    unsigned short* Wl1 = (unsigned short*)take(128 * 128 * 2);
    unsigned short* Wh2 = (unsigned short*)take(128 * 128 * 2);
    unsigned short* Wl2 = (unsigned short*)take(128 * 128 * 2);
    unsigned short* Wh3 = (unsigned short*)take(128 * 64 * 2);
    unsigned short* Wl3 = (unsigned short*)take(128 * 64 * 2);
    bool use_mfma = (off <= ws_size);

    // ---- preprocessing scratch ALIASED onto Ah/Al/hbuf (dead until mm0) ----
    char* pre = (char*)Ah;
    const int R = ((n + NRANGE * 64 - 1) / (NRANGE * 64)) * 64;     // 6272 for n=50000
    const size_t cntSz = align_up((size_t)NRANGE * NCHUNK * R * 4, 256);  // 12.85 MB
    int* cnt_s = (int*)pre;
    int* cnt_d = (int*)(pre + cntSz);
    int* cbase = (int*)(pre + 2 * cntSz);
    int* pos   = (int*)(pre + 3 * cntSz);

    const int aggGrid = (n + 15) / 16;

    if (R <= RMAX) {
        // ---- LDS-privatized preprocessing: zero global atomics ----
        const int E = (ne + NCHUNK - 1) / NCHUNK;
        k_hist<<<NRANGE * NCHUNK, 256, 0, stream>>>(src, dst, ne, R, E, cnt_s, cnt_d, pos);
        k_reduce_norms<<<(NRANGE * R + 255) / 256, 256, 0, stream>>>(cnt_s, cnt_d, R, n,
                                                                     onrm, inrm, degd_sum);
        k_scan<<<1, 1024, 0, stream>>>(degd_sum, n, row_ptr);
        k_cursors<<<(NRANGE * R + 255) / 256, 256, 0, stream>>>(row_ptr, cnt_d, R, n, cbase);
        k_csr_scatter<<<(ne + 255) / 256, 256, 0, stream>>>(src, dst, pos, cbase, ne, R, E, eidx);
        k_sortnode<<<(n + 255) / 256, 256, 0, stream>>>(row_ptr, eidx, eidx2, n, R);
    } else {
        int* degs   = cnt_s;
        int* degd   = cnt_s + n_pad;
        int* cursor = cnt_s + 2 * n_pad;
        hipMemsetAsync(degs, 0, (size_t)2 * n_pad * 4, stream);
        k_degrees_leg<<<(ne + 255) / 256, 256, 0, stream>>>(src, dst, ne, degs, degd);
        k_norms_leg<<<(n + 255) / 256, 256, 0, stream>>>(degs, degd, onrm, inrm, degd_sum, n);
        k_scan<<<1, 1024, 0, stream>>>(degd_sum, n, row_ptr);
        k_copy_int<<<(n + 255) / 256, 256, 0, stream>>>(row_ptr, cursor, n);
        k_build_csr_leg<<<(ne + 255) / 256, 256, 0, stream>>>(src, dst, ne, cursor, eidx);
        k_sortnode<<<(n + 255) / 256, 256, 0, stream>>>(row_ptr, eidx, eidx2,
                                                        n, (n + 7) / 8);
    }

    if (use_mfma) {
        k_split_w_all<<<(73728 + 255) / 256, 256, 0, stream>>>(
            W0, W1, W2, W3, Wh0, Wl0, Wh1, Wl1, Wh2, Wl2, Wh3, Wl3);

        const int mmGrid = n_pad / 128;
        // L0: 256 -> 128, A = x fp32 (split fused, onrm folded)
        k_mm<256, 128, true><<<mmGrid, 256, 0, stream>>>(nullptr, nullptr, x, onrm, Wh0, Wl0, hbuf, n);
        k_agg128_split<<<aggGrid, 256, 0, stream>>>(hbuf, row_ptr, eidx2, inrm, onrm, b0, Ah, Al, n);
        // L1
        k_mm<128, 128, false><<<mmGrid, 256, 0, stream>>>(Ah, Al, nullptr, nullptr, Wh1, Wl1, hbuf, n);
        k_agg128_split<<<aggGrid, 256, 0, stream>>>(hbuf, row_ptr, eidx2, inrm, onrm, b1, Ah, Al, n);
        // L2
        k_mm<128, 128, false><<<mmGrid, 256, 0, stream>>>(Ah, Al, nullptr, nullptr, Wh2, Wl2, hbuf, n);
        k_agg128_split<<<aggGrid, 256, 0, stream>>>(hbuf, row_ptr, eidx2, inrm, onrm, b2, Ah, Al, n);
        // L3: 128 -> 64
        k_mm<128, 64, false><<<mmGrid, 256, 0, stream>>>(Ah, Al, nullptr, nullptr, Wh3, Wl3, hbuf, n);
        k_agg64<<<aggGrid, 256, 0, stream>>>(hbuf, row_ptr, eidx2, inrm, b3, (float*)d_out, n);
    } else {
        // fp32 fallback
        off = off_save;
        float* hbufF  = (float*)take((size_t)n * 128 * 4);
        float* xnextF = (float*)take((size_t)n * 128 * 4);
        const int aggGridF = (n + 3) / 4;

        k_matmul<256, 128, 32, 8, 4><<<(n + 31) / 32, dim3(32, 8), 0, stream>>>(x, W0, onrm, hbufF, n);
        k_agg128f<<<aggGridF, 256, 0, stream>>>(hbufF, row_ptr, eidx2, inrm, b0, xnextF, n, 1);
        k_matmul<128, 128, 32, 8, 4><<<(n + 31) / 32, dim3(32, 8), 0, stream>>>(xnextF, W1, onrm, hbufF, n);
        k_agg128f<<<aggGridF, 256, 0, stream>>>(hbufF, row_ptr, eidx2, inrm, b1, xnextF, n, 1);
        k_matmul<128, 128, 32, 8, 4><<<(n + 31) / 32, dim3(32, 8), 0, stream>>>(xnextF, W2, onrm, hbufF, n);
        k_agg128f<<<aggGridF, 256, 0, stream>>>(hbufF, row_ptr, eidx2, inrm, b2, xnextF, n, 1);
        k_matmul<128, 64, 16, 16, 4><<<(n + 63) / 64, dim3(16, 16), 0, stream>>>(xnextF, W3, onrm, hbufF, n);
        k_agg64f<<<aggGridF, 256, 0, stream>>>(hbufF, row_ptr, eidx2, inrm, b3, (float*)d_out, n);
    }
}